// Round 13
// baseline (198.564 us; speedup 1.0000x reference)
//
#include <hip/hip_runtime.h>
#include <math.h>

#define LSEQ 256
#define NB   128

typedef unsigned short u16;
typedef unsigned int   u32;
typedef __attribute__((ext_vector_type(8))) short bf16x8;  // 8 bf16 = 4 VGPR
typedef __attribute__((ext_vector_type(4))) float f32x4;

static __device__ __forceinline__ u16 f2bf(float x) {
    union { float f; u32 u; } v; v.f = x;
    const u32 r = v.u + 0x7fffu + ((v.u >> 16) & 1u);   // RNE
    return (u16)(r >> 16);
}
// packed f32x2 -> bf16x2 in one VALU op (RNE), lo in low 16 bits
static __device__ __forceinline__ u32 cvt_pk(float lo, float hi) {
    u32 r; asm("v_cvt_pk_bf16_f32 %0, %1, %2" : "=v"(r) : "v"(lo), "v"(hi));
    return r;
}
static __device__ __forceinline__ u16 f2bf_fast(float x) {
    u32 r; asm("v_cvt_pk_bf16_f32 %0, %1, %1" : "=v"(r) : "v"(x));
    return (u16)r;
}
// async global->LDS, 16B per lane, dest = wave-uniform base + lane*16
static __device__ __forceinline__ void glds16(const u16* src, u16* dst) {
    __builtin_amdgcn_global_load_lds(
        (const __attribute__((address_space(1))) u32*)src,
        (__attribute__((address_space(3))) u32*)dst, 16, 0, 0);
}
// barrier that waits LDS ops only — leaves vmem loads in flight (T4)
static __device__ __forceinline__ void bar_lgkm() {
    asm volatile("s_waitcnt lgkmcnt(0)" ::: "memory");
    __builtin_amdgcn_s_barrier();
}
// barrier that waits all own vmem (glds) then syncs — counted-drain barrier
static __device__ __forceinline__ void bar_vm0() {
    asm volatile("s_waitcnt vmcnt(0)" ::: "memory");
    __builtin_amdgcn_s_barrier();
}

// ---------------------------------------------------------------------------
// Dense bf16 MFMA GEMM (non-batched). Block = 128 rows x 256 cols, 512 thr =
// 8 waves (2x4), wave tile 64x64 (4x4 frags of 16x16x32). BK=64.
// A bf16 [M][lda] (K mult 64), B bf16 [N][ldb] (pre-transposed weights).
// EPI 0: C = (acc [+bias gc<Nbias]) [relu] ; EPI 2: fused masked row-pool.
// ---------------------------------------------------------------------------
template<int EPI, bool BIAS, bool RELU>
__global__ __launch_bounds__(512)
void gemm(const u16* __restrict__ A, int lda,
          const u16* __restrict__ B, int ldb,
          u16* __restrict__ C, int ldc,
          const float* __restrict__ bias, int Nbias,
          float* __restrict__ pool, const float* __restrict__ pmask,
          int K, int Nwrite)
{
    __shared__ u16 As[128 * 64];   // 16 KB
    __shared__ u16 Bs[256 * 64];   // 32 KB

    const int m0 = blockIdx.y * 128;
    const int n0 = blockIdx.x * 256;
    const int t = threadIdx.x;
    const int lane = t & 63;
    const int w = t >> 6;
    const int wm = w >> 2;
    const int wn = w & 3;
    const int lr = lane & 15;
    const int lg = lane >> 4;

    f32x4 acc[4][4] = {};

    for (int k0 = 0; k0 < K; k0 += 64) {
#pragma unroll
        for (int i = 0; i < 2; ++i) {
            const int ch = w * 2 + i;
            const int row = (ch << 3) + (lane >> 3);
            const int slot = (lane & 7) ^ (row & 7);
            glds16(A + (long long)(m0 + row) * lda + k0 + (slot << 3), &As[ch << 9]);
        }
#pragma unroll
        for (int i = 0; i < 4; ++i) {
            const int ch = w * 4 + i;
            const int row = (ch << 3) + (lane >> 3);
            const int slot = (lane & 7) ^ (row & 7);
            glds16(B + (long long)(n0 + row) * ldb + k0 + (slot << 3), &Bs[ch << 9]);
        }
        __syncthreads();
#pragma unroll
        for (int kk = 0; kk < 2; ++kk) {
            bf16x8 af[4], bf[4];
#pragma unroll
            for (int mi = 0; mi < 4; ++mi) {
                const int row = wm * 64 + mi * 16 + lr;
                const int slot = ((kk << 2) + lg) ^ (row & 7);
                af[mi] = *reinterpret_cast<const bf16x8*>(&As[row * 64 + (slot << 3)]);
            }
#pragma unroll
            for (int ni = 0; ni < 4; ++ni) {
                const int row = wn * 64 + ni * 16 + lr;
                const int slot = ((kk << 2) + lg) ^ (row & 7);
                bf[ni] = *reinterpret_cast<const bf16x8*>(&Bs[row * 64 + (slot << 3)]);
            }
#pragma unroll
            for (int mi = 0; mi < 4; ++mi)
#pragma unroll
                for (int ni = 0; ni < 4; ++ni)
                    acc[mi][ni] = __builtin_amdgcn_mfma_f32_16x16x32_bf16(
                        af[mi], bf[ni], acc[mi][ni], 0, 0, 0);
        }
        __syncthreads();
    }

    const int rbase = lg << 2;
    if (EPI == 0) {
#pragma unroll
        for (int ni = 0; ni < 4; ++ni) {
            const int gc = n0 + wn * 64 + ni * 16 + lr;
            if (gc >= Nwrite) continue;
            float bcv = 0.f;
            if (BIAS) bcv = (gc < Nbias) ? bias[gc] : 0.f;
#pragma unroll
            for (int mi = 0; mi < 4; ++mi) {
#pragma unroll
                for (int r = 0; r < 4; ++r) {
                    const long long gr = m0 + wm * 64 + mi * 16 + rbase + r;
                    float x = acc[mi][ni][r];
                    if (BIAS) x += bcv;
                    if (RELU) x = fmaxf(x, 0.f);
                    C[gr * ldc + gc] = f2bf_fast(x);
                }
            }
        }
    } else {
        // fused compare epilogue: pool[b][side*400+gc] += relu(acc+bc)*mask[row]
        __syncthreads();
        float* pool_s = reinterpret_cast<float*>(As);
        for (int i = t; i < 256; i += 512) pool_s[i] = 0.f;
        __syncthreads();
        const int b_lin = m0 >> 8;
        const int side  = b_lin >> 7;
        const int bb    = b_lin & 127;
        const float* mk = pmask + b_lin * 256 + (m0 & 255);
        float mrow[4][4];
#pragma unroll
        for (int mi = 0; mi < 4; ++mi)
#pragma unroll
            for (int r = 0; r < 4; ++r)
                mrow[mi][r] = mk[wm * 64 + mi * 16 + rbase + r];
#pragma unroll
        for (int ni = 0; ni < 4; ++ni) {
            const int lc = wn * 64 + ni * 16 + lr;
            const int gc = n0 + lc;
            const float bcv = (BIAS && gc < Nbias) ? bias[gc] : 0.f;
            float cs = 0.f;
#pragma unroll
            for (int mi = 0; mi < 4; ++mi)
#pragma unroll
                for (int r = 0; r < 4; ++r)
                    cs += fmaxf(acc[mi][ni][r] + bcv, 0.f) * mrow[mi][r];
            cs += __shfl_xor(cs, 16, 64);
            cs += __shfl_xor(cs, 32, 64);
            if (lg == 0) atomicAdd(&pool_s[lc], cs);
        }
        __syncthreads();
        for (int i = t; i < 256; i += 512) {
            const int gc = n0 + i;
            if (gc < Nwrite) atomicAdd(&pool[bb * 800 + side * 400 + gc], pool_s[i]);
        }
    }
}

// ---------------------------------------------------------------------------
// Fused flash attention. MODE 0 = intra (dist-bias, V=e NV=320), MODE 1 =
// cross (masked, V=P NV=256/248). One block = (batch-side, half[, variant]).
// QK: BK=32 dbuf, ONE raw barrier per iter: [vmcnt(0); s_barrier; glds(next);
// ds_read(cur); MFMA] — glds fly through the following iteration's compute
// (T4: no __syncthreads vmem drain). Race-free: readers of the buffer being
// overwritten completed their ds_reads before passing this barrier.
// Dist-bias uses softmax shift-invariance: x + bd*[d>=10] == x - bd*[d<10],
// applied only by waves whose tile touches the |i-j|<10 band (wave-uniform
// scalar branch). Softmax/PV barriers are lgkmcnt-only so the T14 V-prefetch
// registers stay in flight across MFMA phases. bf16 packing via
// v_cvt_pk_bf16_f32 (1 op/pair).
// ---------------------------------------------------------------------------
template<int MODE>
__global__ __launch_bounds__(512)
void fattn(const u16* __restrict__ QK, u16* __restrict__ Hb,
           u16* __restrict__ CMP, u16* __restrict__ CMP2,
           const float* __restrict__ M1, const float* __restrict__ M2,
           const float* __restrict__ b_dist)
{
    constexpr int NVT = (MODE == 0) ? 5 : 4;      // V col tiles of 64
    __shared__ __align__(16) char shmem[MODE == 0 ? 57344 : 49152];
    u16* Ks0 = (u16*)shmem;
    u16* Ks1 = (u16*)(shmem + 16384);
    u16* Qs0 = (u16*)(shmem + 32768);
    u16* Qs1 = (u16*)(shmem + 40960);
    u16* Pc = (u16*)shmem;                        // [128][64] 16 KB (PV)
    u16* Vc = (u16*)(shmem + 16384);              // [NVT*64][64] (PV)
    float* red  = (float*)shmem;                  // [128][4]
    float* red2 = red + 512;                      // [128][4]

    const int bz = blockIdx.x;
    int b, half, rowoff, ldv, ldc, Nwrite;
    const u16 *Kp, *Qp, *Vp;
    u16* Cp;
    const float *mrow = nullptr, *mcol = nullptr;
    if (MODE == 0) {
        b = (bz & 7) + (bz >> 4) * 8;             // sibling halves share XCD
        half = (bz >> 3) & 1;
        Kp = QK + (long long)b * 65536;
        Qp = Kp;                                  // queries read from Ks
        Vp = Hb + (long long)b * 163840; ldv = 640;
        Cp = Hb + (long long)b * 163840 + half * 128 * 640 + 320;
        ldc = 640; Nwrite = 320; rowoff = half * 128;
    } else {
        const int xcd = bz & 7, j = bz >> 3;
        const int sib = j & 3;
        b = xcd + (j >> 2) * 8;
        half = sib & 1;
        const int v = sib >> 1;
        const u16* a1 = QK + (long long)b * 65536;
        const u16* a2 = QK + 32768LL * 256 + (long long)b * 65536;
        u16* P1 = CMP  + (long long)b * 114688;
        u16* P2 = CMP2 + (long long)b * 114688;
        if (v == 0) { Qp = a1 + half * 128 * 256; Kp = a2; Vp = P2;
                      Cp = P1 + half * 128 * 448 + 200;
                      mrow = M1 + b * 256 + half * 128; mcol = M2 + b * 256; }
        else        { Qp = a2 + half * 128 * 256; Kp = a1; Vp = P1;
                      Cp = P2 + half * 128 * 448 + 200;
                      mrow = M2 + b * 256 + half * 128; mcol = M1 + b * 256; }
        ldv = 448; ldc = 448; Nwrite = 248; rowoff = 0;
    }

    const int t = threadIdx.x, lane = t & 63, w = t >> 6;
    const int lr = lane & 15, lg = lane >> 4;
    const int wk = w >> 1, wr = w & 1;            // QK wave roles
    const int wr2 = w >> 2, wc = w & 3;           // PV wave roles

    // ---- QK: D[k=256][q=128] = K @ Q^T, BK=32 dbuf, 1 raw barrier/iter ---
    f32x4 acc[4][4] = {};                         // [ki][qi]
    {
        const int krow = (lane >> 2);             // 0..15 within chunk
        const int kslot = (lane & 3) ^ (krow & 3);
        // prologue: stage buf0, k0=0
#pragma unroll
        for (int i = 0; i < 2; ++i) {
            const int ch = w * 2 + i;
            glds16(Kp + (long long)(ch * 16 + krow) * 256 + (kslot << 3), Ks0 + (ch << 9));
        }
        if (MODE != 0)
            glds16(Qp + (long long)(w * 16 + krow) * 256 + (kslot << 3), Qs0 + (w << 9));
        for (int it = 0; it < 8; ++it) {
            // cur-buf glds done (own) + all waves synced (=> all glds done,
            // and all prior readers of the next-stage buffer are finished)
            bar_vm0();
            if (it < 7) {
                const int k0 = (it + 1) * 32;
                u16* kb2 = ((it + 1) & 1) ? Ks1 : Ks0;
#pragma unroll
                for (int i = 0; i < 2; ++i) {
                    const int ch = w * 2 + i;
                    glds16(Kp + (long long)(ch * 16 + krow) * 256 + k0 + (kslot << 3),
                           kb2 + (ch << 9));
                }
                if (MODE != 0) {
                    u16* qb2 = ((it + 1) & 1) ? Qs1 : Qs0;
                    glds16(Qp + (long long)(w * 16 + krow) * 256 + k0 + (kslot << 3),
                           qb2 + (w << 9));
                }
            }
            const u16* kb = (it & 1) ? Ks1 : Ks0;
            const u16* qb = (MODE == 0) ? kb : ((it & 1) ? Qs1 : Qs0);
            bf16x8 kf[4], qf[4];
#pragma unroll
            for (int ki = 0; ki < 4; ++ki) {
                const int row = wk * 64 + ki * 16 + lr;
                kf[ki] = *reinterpret_cast<const bf16x8*>(
                    &kb[row * 32 + ((lg ^ (row & 3)) << 3)]);
            }
#pragma unroll
            for (int qi = 0; qi < 4; ++qi) {
                const int row = (MODE == 0 ? rowoff : 0) + wr * 64 + qi * 16 + lr;
                qf[qi] = *reinterpret_cast<const bf16x8*>(
                    &qb[row * 32 + ((lg ^ (row & 3)) << 3)]);
            }
            __builtin_amdgcn_s_setprio(1);
#pragma unroll
            for (int ki = 0; ki < 4; ++ki)
#pragma unroll
                for (int qi = 0; qi < 4; ++qi)
                    acc[ki][qi] = __builtin_amdgcn_mfma_f32_16x16x32_bf16(
                        kf[ki], qf[qi], acc[ki][qi], 0, 0, 0);
            __builtin_amdgcn_s_setprio(0);
        }
    }

    // ---- pre-softmax transform ------------------------------------------
    if (MODE == 1) {
        float mr[4], mc[4][4];
#pragma unroll
        for (int qi = 0; qi < 4; ++qi) mr[qi] = mrow[wr * 64 + qi * 16 + lr];
#pragma unroll
        for (int ki = 0; ki < 4; ++ki)
#pragma unroll
            for (int r = 0; r < 4; ++r)
                mc[ki][r] = mcol[wk * 64 + ki * 16 + (lg << 2) + r];
#pragma unroll
        for (int ki = 0; ki < 4; ++ki)
#pragma unroll
            for (int qi = 0; qi < 4; ++qi)
#pragma unroll
                for (int r = 0; r < 4; ++r)
                    acc[ki][qi][r] *= mr[qi] * mc[ki][r];
    } else {
        // softmax shift-invariance: x + bd*[d>=10] row-equiv to x - bd*[d<10].
        // Only tiles touching |i-j|<=9 need work; test is wave-uniform.
        const float bd = b_dist[0];
#pragma unroll
        for (int ki = 0; ki < 4; ++ki) {
            const int kb_ = wk * 64 + ki * 16;
#pragma unroll
            for (int qi = 0; qi < 4; ++qi) {
                const int qb_ = rowoff + wr * 64 + qi * 16;
                const int diff = qb_ - kb_;       // wave-uniform
                if (diff >= -24 && diff <= 24) {
                    const int irow = qb_ + lr;
                    const int jc0  = kb_ + (lg << 2);
#pragma unroll
                    for (int r = 0; r < 4; ++r) {
                        const int d = irow - (jc0 + r);
                        const int ad = d < 0 ? -d : d;
                        if (ad < 10) acc[ki][qi][r] -= bd;
                    }
                }
            }
        }
    }

    // ---- T14: issue chunk-0 V loads now (latency hidden under softmax) ---
    const int n4  = (t & 63) << 2;
    const int k8v = (t >> 6) << 3;
    const int n4b = 256 + ((t & 15) << 2);
    const int k8b = (t >> 4) << 3;
    uint2 vreg[8], vtail[8];
#pragma unroll
    for (int i = 0; i < 8; ++i)
        vreg[i] = *reinterpret_cast<const uint2*>(Vp + (long long)(k8v + i) * ldv + n4);
    if (NVT == 5) {
        if (t < 128) {
#pragma unroll
            for (int i = 0; i < 8; ++i)
                vtail[i] = *reinterpret_cast<const uint2*>(Vp + (long long)(k8b + i) * ldv + n4b);
        }
    }

    // ---- softmax over k (cross-wave via LDS; lgkm-only barriers) ---------
    float mx[4];
#pragma unroll
    for (int qi = 0; qi < 4; ++qi) {
        float m_ = -1e30f;
#pragma unroll
        for (int ki = 0; ki < 4; ++ki)
#pragma unroll
            for (int r = 0; r < 4; ++r) m_ = fmaxf(m_, acc[ki][qi][r]);
        m_ = fmaxf(m_, __shfl_xor(m_, 16, 64));
        m_ = fmaxf(m_, __shfl_xor(m_, 32, 64));
        mx[qi] = m_;
    }
    if (lg == 0) {
#pragma unroll
        for (int qi = 0; qi < 4; ++qi)
            red[(wr * 64 + qi * 16 + lr) * 4 + wk] = mx[qi];
    }
    bar_lgkm();
    float sm[4];
#pragma unroll
    for (int qi = 0; qi < 4; ++qi) {
        const int row = wr * 64 + qi * 16 + lr;
        const float m_ = fmaxf(fmaxf(red[row * 4 + 0], red[row * 4 + 1]),
                               fmaxf(red[row * 4 + 2], red[row * 4 + 3]));
        float s_ = 0.f;
#pragma unroll
        for (int ki = 0; ki < 4; ++ki)
#pragma unroll
            for (int r = 0; r < 4; ++r) {
                const float e_ = __expf(acc[ki][qi][r] - m_);
                acc[ki][qi][r] = e_;
                s_ += e_;
            }
        s_ += __shfl_xor(s_, 16, 64);
        s_ += __shfl_xor(s_, 32, 64);
        sm[qi] = s_;
    }
    if (lg == 0) {
#pragma unroll
        for (int qi = 0; qi < 4; ++qi)
            red2[(wr * 64 + qi * 16 + lr) * 4 + wk] = sm[qi];
    }
    bar_lgkm();
#pragma unroll
    for (int qi = 0; qi < 4; ++qi) {
        const int row = wr * 64 + qi * 16 + lr;
        const float rs = 1.0f / (red2[row * 4 + 0] + red2[row * 4 + 1]
                               + red2[row * 4 + 2] + red2[row * 4 + 3]);
#pragma unroll
        for (int ki = 0; ki < 4; ++ki)
#pragma unroll
            for (int r = 0; r < 4; ++r) acc[ki][qi][r] *= rs;
    }
    bar_lgkm();   // red/red2 (Pc region) about to be overwritten

    // ---- PV: out[q=128][NV] = probs @ V, k loop in 4 chunks of 64 --------
    f32x4 opv[4][NVT] = {};
    for (int c = 0; c < 4; ++c) {
        // pack + write V chunk c from prefetched regs
        {
            union { uint2 q2[8]; u16 s[32]; } uq;
#pragma unroll
            for (int i = 0; i < 8; ++i) uq.q2[i] = vreg[i];
#pragma unroll
            for (int j = 0; j < 4; ++j) {
                const int row = n4 + j;
                const u32 v0 = (u32)uq.s[j]      | ((u32)uq.s[4 + j]  << 16);
                const u32 v1 = (u32)uq.s[8 + j]  | ((u32)uq.s[12 + j] << 16);
                const u32 v2 = (u32)uq.s[16 + j] | ((u32)uq.s[20 + j] << 16);
                const u32 v3 = (u32)uq.s[24 + j] | ((u32)uq.s[28 + j] << 16);
                const int slot = (t >> 6) ^ (row & 7);
                *reinterpret_cast<uint4*>(&Vc[row * 64 + (slot << 3)]) =
                    make_uint4(v0, v1, v2, v3);
            }
            if (NVT == 5 && t < 128) {
                union { uint2 q2[8]; u16 s[32]; } ub;
#pragma unroll
                for (int i = 0; i < 8; ++i) ub.q2[i] = vtail[i];
#pragma unroll
                for (int j = 0; j < 4; ++j) {
                    const int row = n4b + j;
                    const u32 v0 = (u32)ub.s[j]      | ((u32)ub.s[4 + j]  << 16);
                    const u32 v1 = (u32)ub.s[8 + j]  | ((u32)ub.s[12 + j] << 16);
                    const u32 v2 = (u32)ub.s[16 + j] | ((u32)ub.s[20 + j] << 16);
                    const u32 v3 = (u32)ub.s[24 + j] | ((u32)ub.s[28 + j] << 16);
                    const int slot = (t >> 4) ^ (row & 7);
                    *reinterpret_cast<uint4*>(&Vc[row * 64 + (slot << 3)]) =
                        make_uint4(v0, v1, v2, v3);
                }
            }
        }
        // owning waves write this chunk's probs (cvt_pk packed b64 writes)
        if (wk == c) {
#pragma unroll
            for (int qi = 0; qi < 4; ++qi) {
                const int qrow = wr * 64 + qi * 16 + lr;
#pragma unroll
                for (int ki = 0; ki < 4; ++ki) {
                    const u32 lo = cvt_pk(acc[ki][qi][0], acc[ki][qi][1]);
                    const u32 hi = cvt_pk(acc[ki][qi][2], acc[ki][qi][3]);
                    const int slot = ((ki << 1) + (lg >> 1)) ^ (qrow & 7);
                    *reinterpret_cast<uint2*>(
                        (char*)Pc + qrow * 128 + (slot << 4) + ((lg & 1) << 3)) =
                        make_uint2(lo, hi);
                }
            }
        }
        // T14: issue next chunk's V loads before this chunk's MFMA — these
        // survive the lgkm-only barriers below and land during the MFMAs.
        if (c < 3) {
#pragma unroll
            for (int i = 0; i < 8; ++i)
                vreg[i] = *reinterpret_cast<const uint2*>(
                    Vp + (long long)((c + 1) * 64 + k8v + i) * ldv + n4);
            if (NVT == 5 && t < 128) {
#pragma unroll
                for (int i = 0; i < 8; ++i)
                    vtail[i] = *reinterpret_cast<const uint2*>(
                        Vp + (long long)((c + 1) * 64 + k8b + i) * ldv + n4b);
            }
        }
        bar_lgkm();   // ds_writes visible; vreg prefetch stays in flight
#pragma unroll
        for (int kk = 0; kk < 2; ++kk) {
            bf16x8 pa[4], vb[NVT];
#pragma unroll
            for (int qi = 0; qi < 4; ++qi) {
                const int row = wr2 * 64 + qi * 16 + lr;
                const int slot = ((kk << 2) + lg) ^ (row & 7);
                pa[qi] = *reinterpret_cast<const bf16x8*>(&Pc[row * 64 + (slot << 3)]);
            }
#pragma unroll
            for (int vi = 0; vi < NVT; ++vi) {
                const int row = wc * (NVT * 16) + vi * 16 + lr;
                const int slot = ((kk << 2) + lg) ^ (row & 7);
                vb[vi] = *reinterpret_cast<const bf16x8*>(&Vc[row * 64 + (slot << 3)]);
            }
            __builtin_amdgcn_s_setprio(1);
#pragma unroll
            for (int qi = 0; qi < 4; ++qi)
#pragma unroll
                for (int vi = 0; vi < NVT; ++vi)
                    opv[qi][vi] = __builtin_amdgcn_mfma_f32_16x16x32_bf16(
                        pa[qi], vb[vi], opv[qi][vi], 0, 0, 0);
            __builtin_amdgcn_s_setprio(0);
        }
        bar_lgkm();   // all reads done before next chunk's ds_writes
    }

    // ---- write out --------------------------------------------------------
#pragma unroll
    for (int qi = 0; qi < 4; ++qi)
#pragma unroll
        for (int vi = 0; vi < NVT; ++vi) {
            const int gc = wc * (NVT * 16) + vi * 16 + lr;
            if (gc >= Nwrite) continue;
#pragma unroll
            for (int r = 0; r < 4; ++r) {
                const int qrow = wr2 * 64 + qi * 16 + (lg << 2) + r;
                Cp[(long long)qrow * ldc + gc] = f2bf_fast(opv[qi][vi][r]);
            }
        }
}

// ---------------------------------------------------------------------------
// Merged prep: blocks 0..16383 gather+L2norm (both sides) -> H;
// blocks 16384..18495 weight transpose+pad -> WiT/WaT/WpT/WcT;
// blocks 18496..18751 masks + POOL zero.
// ---------------------------------------------------------------------------
__global__ __launch_bounds__(256)
void prep_all(const int* __restrict__ x1, const int* __restrict__ x2,
              const float* __restrict__ emb,
              const float* __restrict__ Wi, const float* __restrict__ Wa,
              const float* __restrict__ Wp, const float* __restrict__ Wc,
              u16* __restrict__ h,
              u16* __restrict__ WiT, u16* __restrict__ WaT,
              u16* __restrict__ WpT, u16* __restrict__ WcT,
              float* __restrict__ M1f, float* __restrict__ POOL)
{
    const int blk = blockIdx.x;
    const int t = threadIdx.x;
    if (blk < 16384) {
        const int lane = t & 63;
        const long long row = (long long)blk * 4 + (t >> 6);
        const int tok = (row < 32768) ? x1[row] : x2[row - 32768];
        const float* er = emb + (long long)tok * 300;
        float vals[5];
        float ss = 0.f;
#pragma unroll
        for (int i = 0; i < 5; ++i) {
            const int c = lane + i * 64;
            const float v = (c < 300) ? er[c] : 0.f;
            vals[i] = v;
            ss = fmaf(v, v, ss);
        }
#pragma unroll
        for (int o = 32; o; o >>= 1) ss += __shfl_xor(ss, o, 64);
        const float inv = 1.0f / sqrtf(ss);
        u16* outp = h + row * 640;
#pragma unroll
        for (int i = 0; i < 5; ++i) {
            const int c = lane + i * 64;
            outp[c] = f2bf(vals[i] * inv);
        }
    } else if (blk < 18496) {
        int idx = (blk - 16384) * 256 + t;
        const float* src; u16* dst; int srcRows, srcCols, dstCols, seg1, seg2;
        if (idx < 81920)       { src = Wi; dst = WiT; srcRows = 300; srcCols = 200; dstCols = 320; seg1 = 300; seg2 = 320; }
        else if (idx < 147456) { idx -= 81920;  src = Wa; dst = WaT; srcRows = 200; srcCols = 200; dstCols = 256; seg1 = 200; seg2 = 256; }
        else if (idx < 311296) { idx -= 147456; src = Wp; dst = WpT; srcRows = 600; srcCols = 200; dstCols = 640; seg1 = 300; seg2 = 320; }
        else                   { idx -= 311296; src = Wc; dst = WcT; srcRows = 400; srcCols = 400; dstCols = 448; seg1 = 400; seg2 = 448; }
        const int n = idx / dstCols, k = idx - n * dstCols;
        int sr = -1;
        if (k < seg1) sr = k;
        else if (k >= seg2 && (k - seg2) < (srcRows - seg1)) sr = seg1 + (k - seg2);
        u16 v = 0;
        if (n < srcCols && sr >= 0) v = f2bf(src[(long long)sr * srcCols + n]);
        dst[idx] = v;
    } else {
        const int b2 = blk - 18496;         // 0..255
        const int b = b2 & 127;
        const int* x = (b2 < 128) ? x1 : x2;
        float* mask = M1f + (b2 < 128 ? 0 : 32768);
        int nz = (x[b * LSEQ + t] != 0) ? 1 : 0;
#pragma unroll
        for (int o = 32; o; o >>= 1) nz += __shfl_xor(nz, o, 64);
        __shared__ int red[4];
        if ((t & 63) == 0) red[t >> 6] = nz;
        __syncthreads();
        const int size = red[0] + red[1] + red[2] + red[3];
        mask[b * LSEQ + t] = (t < size) ? 1.0f : 0.0f;
        if (b2 < 128) {
            for (int i = t; i < 800; i += 256) POOL[b * 800 + i] = 0.f;
        }
    }
}

__global__ __launch_bounds__(256)
void final_fc(const float* __restrict__ pooled, const float* __restrict__ Wg,
              const float* __restrict__ bg, float* __restrict__ out)
{
    const int b = blockIdx.x;
    const int t = threadIdx.x;
    float a0 = 0.f, a1 = 0.f, a2 = 0.f;
    for (int k = t; k < 800; k += 256) {
        const float p = pooled[(long long)b * 800 + k];
        a0 = fmaf(p, Wg[k * 3 + 0], a0);
        a1 = fmaf(p, Wg[k * 3 + 1], a1);
        a2 = fmaf(p, Wg[k * 3 + 2], a2);
    }
#pragma unroll
    for (int o = 32; o; o >>= 1) {
        a0 += __shfl_xor(a0, o, 64);
        a1 += __shfl_xor(a1, o, 64);
        a2 += __shfl_xor(a2, o, 64);
    }
    __shared__ float r0[4], r1[4], r2[4];
    if ((t & 63) == 0) { r0[t >> 6] = a0; r1[t >> 6] = a1; r2[t >> 6] = a2; }
    __syncthreads();
    if (t == 0) {
        out[b * 3 + 0] = r0[0] + r0[1] + r0[2] + r0[3] + bg[0];
        out[b * 3 + 1] = r1[0] + r1[1] + r1[2] + r1[3] + bg[1];
        out[b * 3 + 2] = r2[0] + r2[1] + r2[2] + r2[3] + bg[2];
    }
}

// ---------------------------------------------------------------------------
extern "C" void kernel_launch(void* const* d_in, const int* in_sizes, int n_in,
                              void* d_out, int out_size, void* d_ws, size_t ws_size,
                              hipStream_t stream)
{
    (void)in_sizes; (void)n_in; (void)out_size; (void)ws_size;

    const int*   x1     = (const int*)  d_in[0];
    const int*   x2     = (const int*)  d_in[1];
    const float* emb    = (const float*)d_in[2];
    const float* Wi     = (const float*)d_in[3];
    const float* bi     = (const float*)d_in[4];
    const float* b_dist = (const float*)d_in[5];
    const float* Wp     = (const float*)d_in[6];
    const float* bp     = (const float*)d_in[7];
    const float* Wa     = (const float*)d_in[8];
    const float* ba     = (const float*)d_in[9];
    const float* Wc     = (const float*)d_in[10];
    const float* bc     = (const float*)d_in[11];
    const float* Wg     = (const float*)d_in[12];
    const float* bg     = (const float*)d_in[13];
    float* out = (float*)d_out;

    // ---- workspace (bf16 u16 unless noted) -------------------------------
    u16* wsu  = (u16*)d_ws;
    u16* H    = wsu;                       // [65536][640] e|0|xp|0
    u16* CMP  = wsu + 41943040;            // [65536][448] P|beta/alpha|0
    u16* FA   = wsu + 71303168;            // [65536][256] f / a
    u16* WiT  = wsu + 88080384;            // [256][320]
    u16* WaT  = wsu + 88162304;            // [256][256]
    u16* WpT  = wsu + 88227840;            // [256][640]
    u16* WcT  = wsu + 88391680;            // [512][448]
    float* fb = (float*)(wsu + 88621056);
    float* POOL = fb;                      // [128][800]
    float* M1f  = fb + 102400;             // [128][256]; M2f = M1f + 32768
    float* M2f  = fb + 135168;

    u16* CMP2 = CMP + (long long)32768 * 448;

    // merged prep: gather (16384) + weights (2112) + masks/pool (256)
    prep_all<<<18752, 256, 0, stream>>>(x1, x2, emb, Wi, Wa, Wp, Wc,
                                        H, WiT, WaT, WpT, WcT, M1f, POOL);

    // f = relu(e @ Wi + bi), both sides -> FA
    gemm<0, true, true><<<dim3(1, 512, 1), 512, 0, stream>>>(
        H, 640, WiT, 320, FA, 256, bi, 200, nullptr, nullptr, 320, 256);
    // fused intra attention: xp = softmax(f@f^T + dbias) @ e -> H cols 320:640
    fattn<0><<<512, 512, 0, stream>>>(FA, H, nullptr, nullptr, nullptr, nullptr, b_dist);
    // P = h @ Wp + bp -> CMP cols 0:256
    gemm<0, true, false><<<dim3(1, 512, 1), 512, 0, stream>>>(
        H, 640, WpT, 640, CMP, 448, bp, 200, nullptr, nullptr, 640, 256);
    // a = relu(P @ Wa + ba) -> FA
    gemm<0, true, true><<<dim3(1, 512, 1), 512, 0, stream>>>(
        CMP, 448, WaT, 256, FA, 256, ba, 200, nullptr, nullptr, 256, 256);
    // fused cross attention: beta/alpha -> CMP/CMP2 cols 200:448
    fattn<1><<<512, 512, 0, stream>>>(FA, nullptr, CMP, CMP2, M1f, M2f, nullptr);
    // compare + masked pool, both sides
    gemm<2, true, true><<<dim3(2, 512, 1), 512, 0, stream>>>(
        CMP, 448, WcT, 448, nullptr, 0, bc, 400, POOL, M1f, 448, 400);

    final_fc<<<NB, 256, 0, stream>>>(POOL, Wg, bg, out);
}

// Round 14
// 198.550 us; speedup vs baseline: 1.0001x; 1.0001x over previous
//
#include <hip/hip_runtime.h>
#include <math.h>

#define LSEQ 256
#define NB   128

typedef unsigned short u16;
typedef unsigned int   u32;
typedef __attribute__((ext_vector_type(8))) short bf16x8;  // 8 bf16 = 4 VGPR
typedef __attribute__((ext_vector_type(4))) float f32x4;

static __device__ __forceinline__ u16 f2bf(float x) {
    union { float f; u32 u; } v; v.f = x;
    const u32 r = v.u + 0x7fffu + ((v.u >> 16) & 1u);   // RNE
    return (u16)(r >> 16);
}
// packed f32x2 -> bf16x2 in one VALU op (RNE), lo in low 16 bits
static __device__ __forceinline__ u32 cvt_pk(float lo, float hi) {
    u32 r; asm("v_cvt_pk_bf16_f32 %0, %1, %2" : "=v"(r) : "v"(lo), "v"(hi));
    return r;
}
static __device__ __forceinline__ u16 f2bf_fast(float x) {
    u32 r; asm("v_cvt_pk_bf16_f32 %0, %1, %1" : "=v"(r) : "v"(x));
    return (u16)r;
}
// async global->LDS, 16B per lane, dest = wave-uniform base + lane*16
static __device__ __forceinline__ void glds16(const u16* src, u16* dst) {
    __builtin_amdgcn_global_load_lds(
        (const __attribute__((address_space(1))) u32*)src,
        (__attribute__((address_space(3))) u32*)dst, 16, 0, 0);
}
// barrier that waits LDS ops only — leaves vmem loads in flight (T4)
static __device__ __forceinline__ void bar_lgkm() {
    asm volatile("s_waitcnt lgkmcnt(0)" ::: "memory");
    __builtin_amdgcn_s_barrier();
}
// barrier that waits all own vmem (glds) then syncs — counted-drain barrier
static __device__ __forceinline__ void bar_vm0() {
    asm volatile("s_waitcnt vmcnt(0)" ::: "memory");
    __builtin_amdgcn_s_barrier();
}

// ---------------------------------------------------------------------------
// Dense bf16 MFMA GEMM (non-batched). Block = 128 rows x 256 cols, 512 thr =
// 8 waves (2x4), wave tile 64x64 (4x4 frags of 16x16x32). BK=64.
// A bf16 [M][lda] (K mult 64), B bf16 [N][ldb] (pre-transposed weights).
// EPI 0: C = (acc [+bias gc<Nbias]) [relu] ; EPI 2: fused masked row-pool.
// ---------------------------------------------------------------------------
template<int EPI, bool BIAS, bool RELU>
__global__ __launch_bounds__(512)
void gemm(const u16* __restrict__ A, int lda,
          const u16* __restrict__ B, int ldb,
          u16* __restrict__ C, int ldc,
          const float* __restrict__ bias, int Nbias,
          float* __restrict__ pool, const float* __restrict__ pmask,
          int K, int Nwrite)
{
    __shared__ u16 As[128 * 64];   // 16 KB
    __shared__ u16 Bs[256 * 64];   // 32 KB

    const int m0 = blockIdx.y * 128;
    const int n0 = blockIdx.x * 256;
    const int t = threadIdx.x;
    const int lane = t & 63;
    const int w = t >> 6;
    const int wm = w >> 2;
    const int wn = w & 3;
    const int lr = lane & 15;
    const int lg = lane >> 4;

    f32x4 acc[4][4] = {};

    for (int k0 = 0; k0 < K; k0 += 64) {
#pragma unroll
        for (int i = 0; i < 2; ++i) {
            const int ch = w * 2 + i;
            const int row = (ch << 3) + (lane >> 3);
            const int slot = (lane & 7) ^ (row & 7);
            glds16(A + (long long)(m0 + row) * lda + k0 + (slot << 3), &As[ch << 9]);
        }
#pragma unroll
        for (int i = 0; i < 4; ++i) {
            const int ch = w * 4 + i;
            const int row = (ch << 3) + (lane >> 3);
            const int slot = (lane & 7) ^ (row & 7);
            glds16(B + (long long)(n0 + row) * ldb + k0 + (slot << 3), &Bs[ch << 9]);
        }
        __syncthreads();
#pragma unroll
        for (int kk = 0; kk < 2; ++kk) {
            bf16x8 af[4], bf[4];
#pragma unroll
            for (int mi = 0; mi < 4; ++mi) {
                const int row = wm * 64 + mi * 16 + lr;
                const int slot = ((kk << 2) + lg) ^ (row & 7);
                af[mi] = *reinterpret_cast<const bf16x8*>(&As[row * 64 + (slot << 3)]);
            }
#pragma unroll
            for (int ni = 0; ni < 4; ++ni) {
                const int row = wn * 64 + ni * 16 + lr;
                const int slot = ((kk << 2) + lg) ^ (row & 7);
                bf[ni] = *reinterpret_cast<const bf16x8*>(&Bs[row * 64 + (slot << 3)]);
            }
#pragma unroll
            for (int mi = 0; mi < 4; ++mi)
#pragma unroll
                for (int ni = 0; ni < 4; ++ni)
                    acc[mi][ni] = __builtin_amdgcn_mfma_f32_16x16x32_bf16(
                        af[mi], bf[ni], acc[mi][ni], 0, 0, 0);
        }
        __syncthreads();
    }

    const int rbase = lg << 2;
    if (EPI == 0) {
#pragma unroll
        for (int ni = 0; ni < 4; ++ni) {
            const int gc = n0 + wn * 64 + ni * 16 + lr;
            if (gc >= Nwrite) continue;
            float bcv = 0.f;
            if (BIAS) bcv = (gc < Nbias) ? bias[gc] : 0.f;
#pragma unroll
            for (int mi = 0; mi < 4; ++mi) {
#pragma unroll
                for (int r = 0; r < 4; ++r) {
                    const long long gr = m0 + wm * 64 + mi * 16 + rbase + r;
                    float x = acc[mi][ni][r];
                    if (BIAS) x += bcv;
                    if (RELU) x = fmaxf(x, 0.f);
                    C[gr * ldc + gc] = f2bf_fast(x);
                }
            }
        }
    } else {
        // fused compare epilogue: pool[b][side*400+gc] += relu(acc+bc)*mask[row]
        __syncthreads();
        float* pool_s = reinterpret_cast<float*>(As);
        for (int i = t; i < 256; i += 512) pool_s[i] = 0.f;
        __syncthreads();
        const int b_lin = m0 >> 8;
        const int side  = b_lin >> 7;
        const int bb    = b_lin & 127;
        const float* mk = pmask + b_lin * 256 + (m0 & 255);
        float mrow[4][4];
#pragma unroll
        for (int mi = 0; mi < 4; ++mi)
#pragma unroll
            for (int r = 0; r < 4; ++r)
                mrow[mi][r] = mk[wm * 64 + mi * 16 + rbase + r];
#pragma unroll
        for (int ni = 0; ni < 4; ++ni) {
            const int lc = wn * 64 + ni * 16 + lr;
            const int gc = n0 + lc;
            const float bcv = (BIAS && gc < Nbias) ? bias[gc] : 0.f;
            float cs = 0.f;
#pragma unroll
            for (int mi = 0; mi < 4; ++mi)
#pragma unroll
                for (int r = 0; r < 4; ++r)
                    cs += fmaxf(acc[mi][ni][r] + bcv, 0.f) * mrow[mi][r];
            cs += __shfl_xor(cs, 16, 64);
            cs += __shfl_xor(cs, 32, 64);
            if (lg == 0) atomicAdd(&pool_s[lc], cs);
        }
        __syncthreads();
        for (int i = t; i < 256; i += 512) {
            const int gc = n0 + i;
            if (gc < Nwrite) atomicAdd(&pool[bb * 800 + side * 400 + gc], pool_s[i]);
        }
    }
}

// ---------------------------------------------------------------------------
// Fused flash attention. MODE 0 = intra (dist-bias, V=e NV=320), MODE 1 =
// cross (masked, V=P NV=256/248). One block = (batch-side, half[, variant]).
// QK: BK=32 dbuf, ONE raw barrier per iter: [vmcnt(0); s_barrier; glds(next);
// ds_read(cur); MFMA] — glds fly through the following iteration's compute
// (T4: no __syncthreads vmem drain). Race-free: readers of the buffer being
// overwritten completed their ds_reads before passing this barrier.
// Dist-bias uses softmax shift-invariance: x + bd*[d>=10] == x - bd*[d<10],
// applied only by waves whose tile touches the |i-j|<10 band (wave-uniform
// scalar branch). Softmax/PV barriers are lgkmcnt-only so the T14 V-prefetch
// registers stay in flight across MFMA phases. bf16 packing via
// v_cvt_pk_bf16_f32 (1 op/pair).
// ---------------------------------------------------------------------------
template<int MODE>
__global__ __launch_bounds__(512)
void fattn(const u16* __restrict__ QK, u16* __restrict__ Hb,
           u16* __restrict__ CMP, u16* __restrict__ CMP2,
           const float* __restrict__ M1, const float* __restrict__ M2,
           const float* __restrict__ b_dist)
{
    constexpr int NVT = (MODE == 0) ? 5 : 4;      // V col tiles of 64
    __shared__ __align__(16) char shmem[MODE == 0 ? 57344 : 49152];
    u16* Ks0 = (u16*)shmem;
    u16* Ks1 = (u16*)(shmem + 16384);
    u16* Qs0 = (u16*)(shmem + 32768);
    u16* Qs1 = (u16*)(shmem + 40960);
    u16* Pc = (u16*)shmem;                        // [128][64] 16 KB (PV)
    u16* Vc = (u16*)(shmem + 16384);              // [NVT*64][64] (PV)
    float* red  = (float*)shmem;                  // [128][4]
    float* red2 = red + 512;                      // [128][4]

    const int bz = blockIdx.x;
    int b, half, rowoff, ldv, ldc, Nwrite;
    const u16 *Kp, *Qp, *Vp;
    u16* Cp;
    const float *mrow = nullptr, *mcol = nullptr;
    if (MODE == 0) {
        b = (bz & 7) + (bz >> 4) * 8;             // sibling halves share XCD
        half = (bz >> 3) & 1;
        Kp = QK + (long long)b * 65536;
        Qp = Kp;                                  // queries read from Ks
        Vp = Hb + (long long)b * 163840; ldv = 640;
        Cp = Hb + (long long)b * 163840 + half * 128 * 640 + 320;
        ldc = 640; Nwrite = 320; rowoff = half * 128;
    } else {
        const int xcd = bz & 7, j = bz >> 3;
        const int sib = j & 3;
        b = xcd + (j >> 2) * 8;
        half = sib & 1;
        const int v = sib >> 1;
        const u16* a1 = QK + (long long)b * 65536;
        const u16* a2 = QK + 32768LL * 256 + (long long)b * 65536;
        u16* P1 = CMP  + (long long)b * 114688;
        u16* P2 = CMP2 + (long long)b * 114688;
        if (v == 0) { Qp = a1 + half * 128 * 256; Kp = a2; Vp = P2;
                      Cp = P1 + half * 128 * 448 + 200;
                      mrow = M1 + b * 256 + half * 128; mcol = M2 + b * 256; }
        else        { Qp = a2 + half * 128 * 256; Kp = a1; Vp = P1;
                      Cp = P2 + half * 128 * 448 + 200;
                      mrow = M2 + b * 256 + half * 128; mcol = M1 + b * 256; }
        ldv = 448; ldc = 448; Nwrite = 248; rowoff = 0;
    }

    const int t = threadIdx.x, lane = t & 63, w = t >> 6;
    const int lr = lane & 15, lg = lane >> 4;
    const int wk = w >> 1, wr = w & 1;            // QK wave roles
    const int wr2 = w >> 2, wc = w & 3;           // PV wave roles

    // ---- QK: D[k=256][q=128] = K @ Q^T, BK=32 dbuf, 1 raw barrier/iter ---
    f32x4 acc[4][4] = {};                         // [ki][qi]
    {
        const int krow = (lane >> 2);             // 0..15 within chunk
        const int kslot = (lane & 3) ^ (krow & 3);
        // prologue: stage buf0, k0=0
#pragma unroll
        for (int i = 0; i < 2; ++i) {
            const int ch = w * 2 + i;
            glds16(Kp + (long long)(ch * 16 + krow) * 256 + (kslot << 3), Ks0 + (ch << 9));
        }
        if (MODE != 0)
            glds16(Qp + (long long)(w * 16 + krow) * 256 + (kslot << 3), Qs0 + (w << 9));
        for (int it = 0; it < 8; ++it) {
            // cur-buf glds done (own) + all waves synced (=> all glds done,
            // and all prior readers of the next-stage buffer are finished)
            bar_vm0();
            if (it < 7) {
                const int k0 = (it + 1) * 32;
                u16* kb2 = ((it + 1) & 1) ? Ks1 : Ks0;
#pragma unroll
                for (int i = 0; i < 2; ++i) {
                    const int ch = w * 2 + i;
                    glds16(Kp + (long long)(ch * 16 + krow) * 256 + k0 + (kslot << 3),
                           kb2 + (ch << 9));
                }
                if (MODE != 0) {
                    u16* qb2 = ((it + 1) & 1) ? Qs1 : Qs0;
                    glds16(Qp + (long long)(w * 16 + krow) * 256 + k0 + (kslot << 3),
                           qb2 + (w << 9));
                }
            }
            const u16* kb = (it & 1) ? Ks1 : Ks0;
            const u16* qb = (MODE == 0) ? kb : ((it & 1) ? Qs1 : Qs0);
            bf16x8 kf[4], qf[4];
#pragma unroll
            for (int ki = 0; ki < 4; ++ki) {
                const int row = wk * 64 + ki * 16 + lr;
                kf[ki] = *reinterpret_cast<const bf16x8*>(
                    &kb[row * 32 + ((lg ^ (row & 3)) << 3)]);
            }
#pragma unroll
            for (int qi = 0; qi < 4; ++qi) {
                const int row = (MODE == 0 ? rowoff : 0) + wr * 64 + qi * 16 + lr;
                qf[qi] = *reinterpret_cast<const bf16x8*>(
                    &qb[row * 32 + ((lg ^ (row & 3)) << 3)]);
            }
            __builtin_amdgcn_s_setprio(1);
#pragma unroll
            for (int ki = 0; ki < 4; ++ki)
#pragma unroll
                for (int qi = 0; qi < 4; ++qi)
                    acc[ki][qi] = __builtin_amdgcn_mfma_f32_16x16x32_bf16(
                        kf[ki], qf[qi], acc[ki][qi], 0, 0, 0);
            __builtin_amdgcn_s_setprio(0);
        }
    }

    // ---- pre-softmax transform ------------------------------------------
    if (MODE == 1) {
        float mr[4], mc[4][4];
#pragma unroll
        for (int qi = 0; qi < 4; ++qi) mr[qi] = mrow[wr * 64 + qi * 16 + lr];
#pragma unroll
        for (int ki = 0; ki < 4; ++ki)
#pragma unroll
            for (int r = 0; r < 4; ++r)
                mc[ki][r] = mcol[wk * 64 + ki * 16 + (lg << 2) + r];
#pragma unroll
        for (int ki = 0; ki < 4; ++ki)
#pragma unroll
            for (int qi = 0; qi < 4; ++qi)
#pragma unroll
                for (int r = 0; r < 4; ++r)
                    acc[ki][qi][r] *= mr[qi] * mc[ki][r];
    } else {
        // softmax shift-invariance: x + bd*[d>=10] row-equiv to x - bd*[d<10].
        // Only tiles touching |i-j|<=9 need work; test is wave-uniform.
        const float bd = b_dist[0];
#pragma unroll
        for (int ki = 0; ki < 4; ++ki) {
            const int kb_ = wk * 64 + ki * 16;
#pragma unroll
            for (int qi = 0; qi < 4; ++qi) {
                const int qb_ = rowoff + wr * 64 + qi * 16;
                const int diff = qb_ - kb_;       // wave-uniform
                if (diff >= -24 && diff <= 24) {
                    const int irow = qb_ + lr;
                    const int jc0  = kb_ + (lg << 2);
#pragma unroll
                    for (int r = 0; r < 4; ++r) {
                        const int d = irow - (jc0 + r);
                        const int ad = d < 0 ? -d : d;
                        if (ad < 10) acc[ki][qi][r] -= bd;
                    }
                }
            }
        }
    }

    // ---- T14: issue chunk-0 V loads now (latency hidden under softmax) ---
    const int n4  = (t & 63) << 2;
    const int k8v = (t >> 6) << 3;
    const int n4b = 256 + ((t & 15) << 2);
    const int k8b = (t >> 4) << 3;
    uint2 vreg[8], vtail[8];
#pragma unroll
    for (int i = 0; i < 8; ++i)
        vreg[i] = *reinterpret_cast<const uint2*>(Vp + (long long)(k8v + i) * ldv + n4);
    if (NVT == 5) {
        if (t < 128) {
#pragma unroll
            for (int i = 0; i < 8; ++i)
                vtail[i] = *reinterpret_cast<const uint2*>(Vp + (long long)(k8b + i) * ldv + n4b);
        }
    }

    // ---- softmax over k (cross-wave via LDS; lgkm-only barriers) ---------
    float mx[4];
#pragma unroll
    for (int qi = 0; qi < 4; ++qi) {
        float m_ = -1e30f;
#pragma unroll
        for (int ki = 0; ki < 4; ++ki)
#pragma unroll
            for (int r = 0; r < 4; ++r) m_ = fmaxf(m_, acc[ki][qi][r]);
        m_ = fmaxf(m_, __shfl_xor(m_, 16, 64));
        m_ = fmaxf(m_, __shfl_xor(m_, 32, 64));
        mx[qi] = m_;
    }
    if (lg == 0) {
#pragma unroll
        for (int qi = 0; qi < 4; ++qi)
            red[(wr * 64 + qi * 16 + lr) * 4 + wk] = mx[qi];
    }
    bar_lgkm();
    float sm[4];
#pragma unroll
    for (int qi = 0; qi < 4; ++qi) {
        const int row = wr * 64 + qi * 16 + lr;
        const float m_ = fmaxf(fmaxf(red[row * 4 + 0], red[row * 4 + 1]),
                               fmaxf(red[row * 4 + 2], red[row * 4 + 3]));
        float s_ = 0.f;
#pragma unroll
        for (int ki = 0; ki < 4; ++ki)
#pragma unroll
            for (int r = 0; r < 4; ++r) {
                const float e_ = __expf(acc[ki][qi][r] - m_);
                acc[ki][qi][r] = e_;
                s_ += e_;
            }
        s_ += __shfl_xor(s_, 16, 64);
        s_ += __shfl_xor(s_, 32, 64);
        sm[qi] = s_;
    }
    if (lg == 0) {
#pragma unroll
        for (int qi = 0; qi < 4; ++qi)
            red2[(wr * 64 + qi * 16 + lr) * 4 + wk] = sm[qi];
    }
    bar_lgkm();
#pragma unroll
    for (int qi = 0; qi < 4; ++qi) {
        const int row = wr * 64 + qi * 16 + lr;
        const float rs = 1.0f / (red2[row * 4 + 0] + red2[row * 4 + 1]
                               + red2[row * 4 + 2] + red2[row * 4 + 3]);
#pragma unroll
        for (int ki = 0; ki < 4; ++ki)
#pragma unroll
            for (int r = 0; r < 4; ++r) acc[ki][qi][r] *= rs;
    }
    bar_lgkm();   // red/red2 (Pc region) about to be overwritten

    // ---- PV: out[q=128][NV] = probs @ V, k loop in 4 chunks of 64 --------
    f32x4 opv[4][NVT] = {};
    for (int c = 0; c < 4; ++c) {
        // pack + write V chunk c from prefetched regs
        {
            union { uint2 q2[8]; u16 s[32]; } uq;
#pragma unroll
            for (int i = 0; i < 8; ++i) uq.q2[i] = vreg[i];
#pragma unroll
            for (int j = 0; j < 4; ++j) {
                const int row = n4 + j;
                const u32 v0 = (u32)uq.s[j]      | ((u32)uq.s[4 + j]  << 16);
                const u32 v1 = (u32)uq.s[8 + j]  | ((u32)uq.s[12 + j] << 16);
                const u32 v2 = (u32)uq.s[16 + j] | ((u32)uq.s[20 + j] << 16);
                const u32 v3 = (u32)uq.s[24 + j] | ((u32)uq.s[28 + j] << 16);
                const int slot = (t >> 6) ^ (row & 7);
                *reinterpret_cast<uint4*>(&Vc[row * 64 + (slot << 3)]) =
                    make_uint4(v0, v1, v2, v3);
            }
            if (NVT == 5 && t < 128) {
                union { uint2 q2[8]; u16 s[32]; } ub;
#pragma unroll
                for (int i = 0; i < 8; ++i) ub.q2[i] = vtail[i];
#pragma unroll
                for (int j = 0; j < 4; ++j) {
                    const int row = n4b + j;
                    const u32 v0 = (u32)ub.s[j]      | ((u32)ub.s[4 + j]  << 16);
                    const u32 v1 = (u32)ub.s[8 + j]  | ((u32)ub.s[12 + j] << 16);
                    const u32 v2 = (u32)ub.s[16 + j] | ((u32)ub.s[20 + j] << 16);
                    const u32 v3 = (u32)ub.s[24 + j] | ((u32)ub.s[28 + j] << 16);
                    const int slot = (t >> 4) ^ (row & 7);
                    *reinterpret_cast<uint4*>(&Vc[row * 64 + (slot << 3)]) =
                        make_uint4(v0, v1, v2, v3);
                }
            }
        }
        // owning waves write this chunk's probs (cvt_pk packed b64 writes)
        if (wk == c) {
#pragma unroll
            for (int qi = 0; qi < 4; ++qi) {
                const int qrow = wr * 64 + qi * 16 + lr;
#pragma unroll
                for (int ki = 0; ki < 4; ++ki) {
                    const u32 lo = cvt_pk(acc[ki][qi][0], acc[ki][qi][1]);
                    const u32 hi = cvt_pk(acc[ki][qi][2], acc[ki][qi][3]);
                    const int slot = ((ki << 1) + (lg >> 1)) ^ (qrow & 7);
                    *reinterpret_cast<uint2*>(
                        (char*)Pc + qrow * 128 + (slot << 4) + ((lg & 1) << 3)) =
                        make_uint2(lo, hi);
                }
            }
        }
        // T14: issue next chunk's V loads before this chunk's MFMA — these
        // survive the lgkm-only barriers below and land during the MFMAs.
        if (c < 3) {
#pragma unroll
            for (int i = 0; i < 8; ++i)
                vreg[i] = *reinterpret_cast<const uint2*>(
                    Vp + (long long)((c + 1) * 64 + k8v + i) * ldv + n4);
            if (NVT == 5 && t < 128) {
#pragma unroll
                for (int i = 0; i < 8; ++i)
                    vtail[i] = *reinterpret_cast<const uint2*>(
                        Vp + (long long)((c + 1) * 64 + k8b + i) * ldv + n4b);
            }
        }
        bar_lgkm();   // ds_writes visible; vreg prefetch stays in flight
#pragma unroll
        for (int kk = 0; kk < 2; ++kk) {
            bf16x8 pa[4], vb[NVT];
#pragma unroll
            for (int qi = 0; qi < 4; ++qi) {
                const int row = wr2 * 64 + qi * 16 + lr;
                const int slot = ((kk << 2) + lg) ^ (row & 7);
                pa[qi] = *reinterpret_cast<const bf16x8*>(&Pc[row * 64 + (slot << 3)]);
            }
#pragma unroll
            for (int vi = 0; vi < NVT; ++vi) {
                const int row = wc * (NVT * 16) + vi * 16 + lr;
                const int slot = ((kk << 2) + lg) ^ (row & 7);
                vb[vi] = *reinterpret_cast<const bf16x8*>(&Vc[row * 64 + (slot << 3)]);
            }
            __builtin_amdgcn_s_setprio(1);
#pragma unroll
            for (int qi = 0; qi < 4; ++qi)
#pragma unroll
                for (int vi = 0; vi < NVT; ++vi)
                    opv[qi][vi] = __builtin_amdgcn_mfma_f32_16x16x32_bf16(
                        pa[qi], vb[vi], opv[qi][vi], 0, 0, 0);
            __builtin_amdgcn_s_setprio(0);
        }
        bar_lgkm();   // all reads done before next chunk's ds_writes
    }

    // ---- write out --------------------------------------------------------
#pragma unroll
    for (int qi = 0; qi < 4; ++qi)
#pragma unroll
        for (int vi = 0; vi < NVT; ++vi) {
            const int gc = wc * (NVT * 16) + vi * 16 + lr;
            if (gc >= Nwrite) continue;
#pragma unroll
            for (int r = 0; r < 4; ++r) {
                const int qrow = wr2 * 64 + qi * 16 + (lg << 2) + r;
                Cp[(long long)qrow * ldc + gc] = f2bf_fast(opv[qi][vi][r]);
            }
        }
}

// ---------------------------------------------------------------------------
// Merged prep: blocks 0..16383 gather+L2norm (both sides) -> H;
// blocks 16384..18495 weight transpose+pad -> WiT/WaT/WpT/WcT;
// blocks 18496..18751 masks + POOL zero.
// ---------------------------------------------------------------------------
__global__ __launch_bounds__(256)
void prep_all(const int* __restrict__ x1, const int* __restrict__ x2,
              const float* __restrict__ emb,
              const float* __restrict__ Wi, const float* __restrict__ Wa,
              const float* __restrict__ Wp, const float* __restrict__ Wc,
              u16* __restrict__ h,
              u16* __restrict__ WiT, u16* __restrict__ WaT,
              u16* __restrict__ WpT, u16* __restrict__ WcT,
              float* __restrict__ M1f, float* __restrict__ POOL)
{
    const int blk = blockIdx.x;
    const int t = threadIdx.x;
    if (blk < 16384) {
        const int lane = t & 63;
        const long long row = (long long)blk * 4 + (t >> 6);
        const int tok = (row < 32768) ? x1[row] : x2[row - 32768];
        const float* er = emb + (long long)tok * 300;
        float vals[5];
        float ss = 0.f;
#pragma unroll
        for (int i = 0; i < 5; ++i) {
            const int c = lane + i * 64;
            const float v = (c < 300) ? er[c] : 0.f;
            vals[i] = v;
            ss = fmaf(v, v, ss);
        }
#pragma unroll
        for (int o = 32; o; o >>= 1) ss += __shfl_xor(ss, o, 64);
        const float inv = 1.0f / sqrtf(ss);
        u16* outp = h + row * 640;
#pragma unroll
        for (int i = 0; i < 5; ++i) {
            const int c = lane + i * 64;
            outp[c] = f2bf(vals[i] * inv);
        }
    } else if (blk < 18496) {
        int idx = (blk - 16384) * 256 + t;
        const float* src; u16* dst; int srcRows, srcCols, dstCols, seg1, seg2;
        if (idx < 81920)       { src = Wi; dst = WiT; srcRows = 300; srcCols = 200; dstCols = 320; seg1 = 300; seg2 = 320; }
        else if (idx < 147456) { idx -= 81920;  src = Wa; dst = WaT; srcRows = 200; srcCols = 200; dstCols = 256; seg1 = 200; seg2 = 256; }
        else if (idx < 311296) { idx -= 147456; src = Wp; dst = WpT; srcRows = 600; srcCols = 200; dstCols = 640; seg1 = 300; seg2 = 320; }
        else                   { idx -= 311296; src = Wc; dst = WcT; srcRows = 400; srcCols = 400; dstCols = 448; seg1 = 400; seg2 = 448; }
        const int n = idx / dstCols, k = idx - n * dstCols;
        int sr = -1;
        if (k < seg1) sr = k;
        else if (k >= seg2 && (k - seg2) < (srcRows - seg1)) sr = seg1 + (k - seg2);
        u16 v = 0;
        if (n < srcCols && sr >= 0) v = f2bf(src[(long long)sr * srcCols + n]);
        dst[idx] = v;
    } else {
        const int b2 = blk - 18496;         // 0..255
        const int b = b2 & 127;
        const int* x = (b2 < 128) ? x1 : x2;
        float* mask = M1f + (b2 < 128 ? 0 : 32768);
        int nz = (x[b * LSEQ + t] != 0) ? 1 : 0;
#pragma unroll
        for (int o = 32; o; o >>= 1) nz += __shfl_xor(nz, o, 64);
        __shared__ int red[4];
        if ((t & 63) == 0) red[t >> 6] = nz;
        __syncthreads();
        const int size = red[0] + red[1] + red[2] + red[3];
        mask[b * LSEQ + t] = (t < size) ? 1.0f : 0.0f;
        if (b2 < 128) {
            for (int i = t; i < 800; i += 256) POOL[b * 800 + i] = 0.f;
        }
    }
}

__global__ __launch_bounds__(256)
void final_fc(const float* __restrict__ pooled, const float* __restrict__ Wg,
              const float* __restrict__ bg, float* __restrict__ out)
{
    const int b = blockIdx.x;
    const int t = threadIdx.x;
    float a0 = 0.f, a1 = 0.f, a2 = 0.f;
    for (int k = t; k < 800; k += 256) {
        const float p = pooled[(long long)b * 800 + k];
        a0 = fmaf(p, Wg[k * 3 + 0], a0);
        a1 = fmaf(p, Wg[k * 3 + 1], a1);
        a2 = fmaf(p, Wg[k * 3 + 2], a2);
    }
#pragma unroll
    for (int o = 32; o; o >>= 1) {
        a0 += __shfl_xor(a0, o, 64);
        a1 += __shfl_xor(a1, o, 64);
        a2 += __shfl_xor(a2, o, 64);
    }
    __shared__ float r0[4], r1[4], r2[4];
    if ((t & 63) == 0) { r0[t >> 6] = a0; r1[t >> 6] = a1; r2[t >> 6] = a2; }
    __syncthreads();
    if (t == 0) {
        out[b * 3 + 0] = r0[0] + r0[1] + r0[2] + r0[3] + bg[0];
        out[b * 3 + 1] = r1[0] + r1[1] + r1[2] + r1[3] + bg[1];
        out[b * 3 + 2] = r2[0] + r2[1] + r2[2] + r2[3] + bg[2];
    }
}

// ---------------------------------------------------------------------------
extern "C" void kernel_launch(void* const* d_in, const int* in_sizes, int n_in,
                              void* d_out, int out_size, void* d_ws, size_t ws_size,
                              hipStream_t stream)
{
    (void)in_sizes; (void)n_in; (void)out_size; (void)ws_size;

    const int*   x1     = (const int*)  d_in[0];
    const int*   x2     = (const int*)  d_in[1];
    const float* emb    = (const float*)d_in[2];
    const float* Wi     = (const float*)d_in[3];
    const float* bi     = (const float*)d_in[4];
    const float* b_dist = (const float*)d_in[5];
    const float* Wp     = (const float*)d_in[6];
    const float* bp     = (const float*)d_in[7];
    const float* Wa     = (const float*)d_in[8];
    const float* ba     = (const float*)d_in[9];
    const float* Wc     = (const float*)d_in[10];
    const float* bc     = (const float*)d_in[11];
    const float* Wg     = (const float*)d_in[12];
    const float* bg     = (const float*)d_in[13];
    float* out = (float*)d_out;

    // ---- workspace (bf16 u16 unless noted) -------------------------------
    u16* wsu  = (u16*)d_ws;
    u16* H    = wsu;                       // [65536][640] e|0|xp|0
    u16* CMP  = wsu + 41943040;            // [65536][448] P|beta/alpha|0
    u16* FA   = wsu + 71303168;            // [65536][256] f / a
    u16* WiT  = wsu + 88080384;            // [256][320]
    u16* WaT  = wsu + 88162304;            // [256][256]
    u16* WpT  = wsu + 88227840;            // [256][640]
    u16* WcT  = wsu + 88391680;            // [512][448]
    float* fb = (float*)(wsu + 88621056);
    float* POOL = fb;                      // [128][800]
    float* M1f  = fb + 102400;             // [128][256]; M2f = M1f + 32768
    float* M2f  = fb + 135168;

    u16* CMP2 = CMP + (long long)32768 * 448;

    // merged prep: gather (16384) + weights (2112) + masks/pool (256)
    prep_all<<<18752, 256, 0, stream>>>(x1, x2, emb, Wi, Wa, Wp, Wc,
                                        H, WiT, WaT, WpT, WcT, M1f, POOL);

    // f = relu(e @ Wi + bi), both sides -> FA
    gemm<0, true, true><<<dim3(1, 512, 1), 512, 0, stream>>>(
        H, 640, WiT, 320, FA, 256, bi, 200, nullptr, nullptr, 320, 256);
    // fused intra attention: xp = softmax(f@f^T + dbias) @ e -> H cols 320:640
    fattn<0><<<512, 512, 0, stream>>>(FA, H, nullptr, nullptr, nullptr, nullptr, b_dist);
    // P = h @ Wp + bp -> CMP cols 0:256
    gemm<0, true, false><<<dim3(1, 512, 1), 512, 0, stream>>>(
        H, 640, WpT, 640, CMP, 448, bp, 200, nullptr, nullptr, 640, 256);
    // a = relu(P @ Wa + ba) -> FA
    gemm<0, true, true><<<dim3(1, 512, 1), 512, 0, stream>>>(
        CMP, 448, WaT, 256, FA, 256, ba, 200, nullptr, nullptr, 256, 256);
    // fused cross attention: beta/alpha -> CMP/CMP2 cols 200:448
    fattn<1><<<512, 512, 0, stream>>>(FA, nullptr, CMP, CMP2, M1f, M2f, nullptr);
    // compare + masked pool, both sides
    gemm<2, true, true><<<dim3(2, 512, 1), 512, 0, stream>>>(
        CMP, 448, WcT, 448, nullptr, 0, bc, 400, POOL, M1f, 448, 400);

    final_fc<<<NB, 256, 0, stream>>>(POOL, Wg, bg, out);
}

// Round 15
// 196.741 us; speedup vs baseline: 1.0093x; 1.0092x over previous
//
#include <hip/hip_runtime.h>
#include <math.h>

#define LSEQ 256
#define NB   128

typedef unsigned short u16;
typedef unsigned int   u32;
typedef __attribute__((ext_vector_type(8))) short bf16x8;  // 8 bf16 = 4 VGPR
typedef __attribute__((ext_vector_type(4))) float f32x4;

static __device__ __forceinline__ u16 f2bf(float x) {
    union { float f; u32 u; } v; v.f = x;
    const u32 r = v.u + 0x7fffu + ((v.u >> 16) & 1u);   // RNE
    return (u16)(r >> 16);
}
// packed f32x2 -> bf16x2 in one VALU op (RNE), lo in low 16 bits
static __device__ __forceinline__ u32 cvt_pk(float lo, float hi) {
    u32 r; asm("v_cvt_pk_bf16_f32 %0, %1, %2" : "=v"(r) : "v"(lo), "v"(hi));
    return r;
}
static __device__ __forceinline__ u16 f2bf_fast(float x) {
    u32 r; asm("v_cvt_pk_bf16_f32 %0, %1, %1" : "=v"(r) : "v"(x));
    return (u16)r;
}
// async global->LDS, 16B per lane, dest = wave-uniform base + lane*16
static __device__ __forceinline__ void glds16(const u16* src, u16* dst) {
    __builtin_amdgcn_global_load_lds(
        (const __attribute__((address_space(1))) u32*)src,
        (__attribute__((address_space(3))) u32*)dst, 16, 0, 0);
}
// barrier that waits LDS ops only — leaves vmem loads in flight (T4)
static __device__ __forceinline__ void bar_lgkm() {
    asm volatile("s_waitcnt lgkmcnt(0)" ::: "memory");
    __builtin_amdgcn_s_barrier();
}

// ---------------------------------------------------------------------------
// Dense bf16 MFMA GEMM (non-batched). Block = 128 rows x 256 cols, 512 thr =
// 8 waves (2x4), wave tile 64x64 (4x4 frags of 16x16x32). BK=64.
// A bf16 [M][lda] (K mult 64), B bf16 [N][ldb] (pre-transposed weights).
// EPI 0: C = (acc [+bias gc<Nbias]) [relu] ; EPI 2: fused masked row-pool.
// ---------------------------------------------------------------------------
template<int EPI, bool BIAS, bool RELU>
__global__ __launch_bounds__(512)
void gemm(const u16* __restrict__ A, int lda,
          const u16* __restrict__ B, int ldb,
          u16* __restrict__ C, int ldc,
          const float* __restrict__ bias, int Nbias,
          float* __restrict__ pool, const float* __restrict__ pmask,
          int K, int Nwrite)
{
    __shared__ u16 As[128 * 64];   // 16 KB
    __shared__ u16 Bs[256 * 64];   // 32 KB

    const int m0 = blockIdx.y * 128;
    const int n0 = blockIdx.x * 256;
    const int t = threadIdx.x;
    const int lane = t & 63;
    const int w = t >> 6;
    const int wm = w >> 2;
    const int wn = w & 3;
    const int lr = lane & 15;
    const int lg = lane >> 4;

    f32x4 acc[4][4] = {};

    for (int k0 = 0; k0 < K; k0 += 64) {
#pragma unroll
        for (int i = 0; i < 2; ++i) {
            const int ch = w * 2 + i;
            const int row = (ch << 3) + (lane >> 3);
            const int slot = (lane & 7) ^ (row & 7);
            glds16(A + (long long)(m0 + row) * lda + k0 + (slot << 3), &As[ch << 9]);
        }
#pragma unroll
        for (int i = 0; i < 4; ++i) {
            const int ch = w * 4 + i;
            const int row = (ch << 3) + (lane >> 3);
            const int slot = (lane & 7) ^ (row & 7);
            glds16(B + (long long)(n0 + row) * ldb + k0 + (slot << 3), &Bs[ch << 9]);
        }
        __syncthreads();
#pragma unroll
        for (int kk = 0; kk < 2; ++kk) {
            bf16x8 af[4], bf[4];
#pragma unroll
            for (int mi = 0; mi < 4; ++mi) {
                const int row = wm * 64 + mi * 16 + lr;
                const int slot = ((kk << 2) + lg) ^ (row & 7);
                af[mi] = *reinterpret_cast<const bf16x8*>(&As[row * 64 + (slot << 3)]);
            }
#pragma unroll
            for (int ni = 0; ni < 4; ++ni) {
                const int row = wn * 64 + ni * 16 + lr;
                const int slot = ((kk << 2) + lg) ^ (row & 7);
                bf[ni] = *reinterpret_cast<const bf16x8*>(&Bs[row * 64 + (slot << 3)]);
            }
#pragma unroll
            for (int mi = 0; mi < 4; ++mi)
#pragma unroll
                for (int ni = 0; ni < 4; ++ni)
                    acc[mi][ni] = __builtin_amdgcn_mfma_f32_16x16x32_bf16(
                        af[mi], bf[ni], acc[mi][ni], 0, 0, 0);
        }
        __syncthreads();
    }

    const int rbase = lg << 2;
    if (EPI == 0) {
#pragma unroll
        for (int ni = 0; ni < 4; ++ni) {
            const int gc = n0 + wn * 64 + ni * 16 + lr;
            if (gc >= Nwrite) continue;
            float bcv = 0.f;
            if (BIAS) bcv = (gc < Nbias) ? bias[gc] : 0.f;
#pragma unroll
            for (int mi = 0; mi < 4; ++mi) {
#pragma unroll
                for (int r = 0; r < 4; ++r) {
                    const long long gr = m0 + wm * 64 + mi * 16 + rbase + r;
                    float x = acc[mi][ni][r];
                    if (BIAS) x += bcv;
                    if (RELU) x = fmaxf(x, 0.f);
                    C[gr * ldc + gc] = f2bf_fast(x);
                }
            }
        }
    } else {
        // fused compare epilogue: pool[b][side*400+gc] += relu(acc+bc)*mask[row]
        __syncthreads();
        float* pool_s = reinterpret_cast<float*>(As);
        for (int i = t; i < 256; i += 512) pool_s[i] = 0.f;
        __syncthreads();
        const int b_lin = m0 >> 8;
        const int side  = b_lin >> 7;
        const int bb    = b_lin & 127;
        const float* mk = pmask + b_lin * 256 + (m0 & 255);
        float mrow[4][4];
#pragma unroll
        for (int mi = 0; mi < 4; ++mi)
#pragma unroll
            for (int r = 0; r < 4; ++r)
                mrow[mi][r] = mk[wm * 64 + mi * 16 + rbase + r];
#pragma unroll
        for (int ni = 0; ni < 4; ++ni) {
            const int lc = wn * 64 + ni * 16 + lr;
            const int gc = n0 + lc;
            const float bcv = (BIAS && gc < Nbias) ? bias[gc] : 0.f;
            float cs = 0.f;
#pragma unroll
            for (int mi = 0; mi < 4; ++mi)
#pragma unroll
                for (int r = 0; r < 4; ++r)
                    cs += fmaxf(acc[mi][ni][r] + bcv, 0.f) * mrow[mi][r];
            cs += __shfl_xor(cs, 16, 64);
            cs += __shfl_xor(cs, 32, 64);
            if (lg == 0) atomicAdd(&pool_s[lc], cs);
        }
        __syncthreads();
        for (int i = t; i < 256; i += 512) {
            const int gc = n0 + i;
            if (gc < Nwrite) atomicAdd(&pool[bb * 800 + side * 400 + gc], pool_s[i]);
        }
    }
}

// ---------------------------------------------------------------------------
// Fused flash attention. MODE 0 = intra (dist-bias, V=e NV=320), MODE 1 =
// cross (masked, V=P NV=256/248). One block = (batch-side, half[, variant]).
// QK (T4 counted-vmcnt, 2-deep prefetch): K rotates 3 LDS buffers, Q (MODE1)
// 2 buffers. Per iter: [vmcnt(2); s_barrier] [issue Q(it+1), K(it+2)]
// [ds_read cur] [MFMA]. vmcnt(2) leaves only K(it+1)'s 2 loads in flight, so
// every glds gets ~2 iterations to land (HBM latency covered). Rotation is
// race-free: a buffer's last readers passed >=1 barrier before its rewrite.
// QK LDS swizzle s(row)=(row^(row>>2))&3 makes the 4 rows per ds_read_b128
// lg-group hit distinct bank quarters (old row&3 was a 4-way conflict).
// Dist-bias via softmax shift-invariance (band waves only). Softmax/PV
// barriers are lgkmcnt-only so T14 V-prefetch stays in flight. cvt_pk packs.
// ---------------------------------------------------------------------------
template<int MODE>
__global__ __launch_bounds__(512)
void fattn(const u16* __restrict__ QK, u16* __restrict__ Hb,
           u16* __restrict__ CMP, u16* __restrict__ CMP2,
           const float* __restrict__ M1, const float* __restrict__ M2,
           const float* __restrict__ b_dist)
{
    constexpr int NVT = (MODE == 0) ? 5 : 4;      // V col tiles of 64
    // MODE0: QK K-bufs 3x16K = 48K; PV Pc16K+Vc40K = 56K -> 57344
    // MODE1: QK K 3x16K + Q 2x8K = 64K; PV Pc16K+Vc32K = 48K -> 65536
    __shared__ __align__(16) char shmem[MODE == 0 ? 57344 : 65536];
    u16* Pc = (u16*)shmem;                        // [128][64] 16 KB (PV)
    u16* Vc = (u16*)(shmem + 16384);              // [NVT*64][64] (PV)
    float* red  = (float*)shmem;                  // [128][4]
    float* red2 = red + 512;                      // [128][4]

    const int bz = blockIdx.x;
    int b, half, rowoff, ldv, ldc, Nwrite;
    const u16 *Kp, *Qp, *Vp;
    u16* Cp;
    const float *mrow = nullptr, *mcol = nullptr;
    if (MODE == 0) {
        b = (bz & 7) + (bz >> 4) * 8;             // sibling halves share XCD
        half = (bz >> 3) & 1;
        Kp = QK + (long long)b * 65536;
        Qp = Kp;                                  // queries read from K bufs
        Vp = Hb + (long long)b * 163840; ldv = 640;
        Cp = Hb + (long long)b * 163840 + half * 128 * 640 + 320;
        ldc = 640; Nwrite = 320; rowoff = half * 128;
    } else {
        const int xcd = bz & 7, j = bz >> 3;
        const int sib = j & 3;
        b = xcd + (j >> 2) * 8;
        half = sib & 1;
        const int v = sib >> 1;
        const u16* a1 = QK + (long long)b * 65536;
        const u16* a2 = QK + 32768LL * 256 + (long long)b * 65536;
        u16* P1 = CMP  + (long long)b * 114688;
        u16* P2 = CMP2 + (long long)b * 114688;
        if (v == 0) { Qp = a1 + half * 128 * 256; Kp = a2; Vp = P2;
                      Cp = P1 + half * 128 * 448 + 200;
                      mrow = M1 + b * 256 + half * 128; mcol = M2 + b * 256; }
        else        { Qp = a2 + half * 128 * 256; Kp = a1; Vp = P1;
                      Cp = P2 + half * 128 * 448 + 200;
                      mrow = M2 + b * 256 + half * 128; mcol = M1 + b * 256; }
        ldv = 448; ldc = 448; Nwrite = 248; rowoff = 0;
    }

    const int t = threadIdx.x, lane = t & 63, w = t >> 6;
    const int lr = lane & 15, lg = lane >> 4;
    const int wk = w >> 1, wr = w & 1;            // QK wave roles
    const int wr2 = w >> 2, wc = w & 3;           // PV wave roles

    // ---- QK: D[k=256][q=128] = K @ Q^T, 3-buf K / 2-buf Q, vmcnt(2) ------
    f32x4 acc[4][4] = {};                         // [ki][qi]
    {
        const int krow = lane >> 2;               // 0..15 within chunk
        const int kslot = (lane & 3) ^ ((krow ^ (krow >> 2)) & 3);
        // prologue: Q(0); K(0); K(1)  (queue: [Q0,K0,K0,K1,K1])
        if (MODE != 0)
            glds16(Qp + (long long)(w * 16 + krow) * 256 + (kslot << 3),
                   (u16*)(shmem + 49152) + (w << 9));
#pragma unroll
        for (int i = 0; i < 2; ++i) {
            const int ch = w * 2 + i;
            glds16(Kp + (long long)(ch * 16 + krow) * 256 + (kslot << 3),
                   (u16*)shmem + (ch << 9));
        }
#pragma unroll
        for (int i = 0; i < 2; ++i) {
            const int ch = w * 2 + i;
            glds16(Kp + (long long)(ch * 16 + krow) * 256 + 32 + (kslot << 3),
                   (u16*)(shmem + 16384) + (ch << 9));
        }
#pragma unroll
        for (int it = 0; it < 8; ++it) {
            // leave only K(it+1)'s 2 loads in flight; drain all on last iter
            if (it == 7) asm volatile("s_waitcnt vmcnt(0)" ::: "memory");
            else         asm volatile("s_waitcnt vmcnt(2)" ::: "memory");
            __builtin_amdgcn_s_barrier();
            if (MODE != 0 && it < 7) {
                u16* qb2 = (u16*)(shmem + 49152 + (((it + 1) & 1) << 13));
                glds16(Qp + (long long)(w * 16 + krow) * 256 + (it + 1) * 32 + (kslot << 3),
                       qb2 + (w << 9));
            }
            if (it < 6) {
                u16* kb2 = (u16*)(shmem + ((it + 2) % 3) * 16384);
#pragma unroll
                for (int i = 0; i < 2; ++i) {
                    const int ch = w * 2 + i;
                    glds16(Kp + (long long)(ch * 16 + krow) * 256 + (it + 2) * 32 + (kslot << 3),
                           kb2 + (ch << 9));
                }
            }
            const u16* kb = (const u16*)(shmem + (it % 3) * 16384);
            const u16* qb = (MODE == 0) ? kb
                          : (const u16*)(shmem + 49152 + ((it & 1) << 13));
            bf16x8 kf[4], qf[4];
#pragma unroll
            for (int ki = 0; ki < 4; ++ki) {
                const int row = wk * 64 + ki * 16 + lr;
                const int phys = lg ^ ((row ^ (row >> 2)) & 3);
                kf[ki] = *reinterpret_cast<const bf16x8*>(&kb[row * 32 + (phys << 3)]);
            }
#pragma unroll
            for (int qi = 0; qi < 4; ++qi) {
                const int row = (MODE == 0 ? rowoff : 0) + wr * 64 + qi * 16 + lr;
                const int phys = lg ^ ((row ^ (row >> 2)) & 3);
                qf[qi] = *reinterpret_cast<const bf16x8*>(&qb[row * 32 + (phys << 3)]);
            }
            __builtin_amdgcn_s_setprio(1);
#pragma unroll
            for (int ki = 0; ki < 4; ++ki)
#pragma unroll
                for (int qi = 0; qi < 4; ++qi)
                    acc[ki][qi] = __builtin_amdgcn_mfma_f32_16x16x32_bf16(
                        kf[ki], qf[qi], acc[ki][qi], 0, 0, 0);
            __builtin_amdgcn_s_setprio(0);
        }
    }

    // ---- pre-softmax transform ------------------------------------------
    if (MODE == 1) {
        float mr[4], mc[4][4];
#pragma unroll
        for (int qi = 0; qi < 4; ++qi) mr[qi] = mrow[wr * 64 + qi * 16 + lr];
#pragma unroll
        for (int ki = 0; ki < 4; ++ki)
#pragma unroll
            for (int r = 0; r < 4; ++r)
                mc[ki][r] = mcol[wk * 64 + ki * 16 + (lg << 2) + r];
#pragma unroll
        for (int ki = 0; ki < 4; ++ki)
#pragma unroll
            for (int qi = 0; qi < 4; ++qi)
#pragma unroll
                for (int r = 0; r < 4; ++r)
                    acc[ki][qi][r] *= mr[qi] * mc[ki][r];
    } else {
        // softmax shift-invariance: x + bd*[d>=10] row-equiv to x - bd*[d<10].
        const float bd = b_dist[0];
#pragma unroll
        for (int ki = 0; ki < 4; ++ki) {
            const int kb_ = wk * 64 + ki * 16;
#pragma unroll
            for (int qi = 0; qi < 4; ++qi) {
                const int qb_ = rowoff + wr * 64 + qi * 16;
                const int diff = qb_ - kb_;       // wave-uniform
                if (diff >= -24 && diff <= 24) {
                    const int irow = qb_ + lr;
                    const int jc0  = kb_ + (lg << 2);
#pragma unroll
                    for (int r = 0; r < 4; ++r) {
                        const int d = irow - (jc0 + r);
                        const int ad = d < 0 ? -d : d;
                        if (ad < 10) acc[ki][qi][r] -= bd;
                    }
                }
            }
        }
    }

    // ---- T14: issue chunk-0 V loads now (latency hidden under softmax) ---
    const int n4  = (t & 63) << 2;
    const int k8v = (t >> 6) << 3;
    const int n4b = 256 + ((t & 15) << 2);
    const int k8b = (t >> 4) << 3;
    uint2 vreg[8], vtail[8];
#pragma unroll
    for (int i = 0; i < 8; ++i)
        vreg[i] = *reinterpret_cast<const uint2*>(Vp + (long long)(k8v + i) * ldv + n4);
    if (NVT == 5) {
        if (t < 128) {
#pragma unroll
            for (int i = 0; i < 8; ++i)
                vtail[i] = *reinterpret_cast<const uint2*>(Vp + (long long)(k8b + i) * ldv + n4b);
        }
    }

    // ---- softmax over k (cross-wave via LDS; lgkm-only barriers) ---------
    float mx[4];
#pragma unroll
    for (int qi = 0; qi < 4; ++qi) {
        float m_ = -1e30f;
#pragma unroll
        for (int ki = 0; ki < 4; ++ki)
#pragma unroll
            for (int r = 0; r < 4; ++r) m_ = fmaxf(m_, acc[ki][qi][r]);
        m_ = fmaxf(m_, __shfl_xor(m_, 16, 64));
        m_ = fmaxf(m_, __shfl_xor(m_, 32, 64));
        mx[qi] = m_;
    }
    if (lg == 0) {
#pragma unroll
        for (int qi = 0; qi < 4; ++qi)
            red[(wr * 64 + qi * 16 + lr) * 4 + wk] = mx[qi];
    }
    bar_lgkm();
    float sm[4];
#pragma unroll
    for (int qi = 0; qi < 4; ++qi) {
        const int row = wr * 64 + qi * 16 + lr;
        const float m_ = fmaxf(fmaxf(red[row * 4 + 0], red[row * 4 + 1]),
                               fmaxf(red[row * 4 + 2], red[row * 4 + 3]));
        float s_ = 0.f;
#pragma unroll
        for (int ki = 0; ki < 4; ++ki)
#pragma unroll
            for (int r = 0; r < 4; ++r) {
                const float e_ = __expf(acc[ki][qi][r] - m_);
                acc[ki][qi][r] = e_;
                s_ += e_;
            }
        s_ += __shfl_xor(s_, 16, 64);
        s_ += __shfl_xor(s_, 32, 64);
        sm[qi] = s_;
    }
    if (lg == 0) {
#pragma unroll
        for (int qi = 0; qi < 4; ++qi)
            red2[(wr * 64 + qi * 16 + lr) * 4 + wk] = sm[qi];
    }
    bar_lgkm();
#pragma unroll
    for (int qi = 0; qi < 4; ++qi) {
        const int row = wr * 64 + qi * 16 + lr;
        const float rs = 1.0f / (red2[row * 4 + 0] + red2[row * 4 + 1]
                               + red2[row * 4 + 2] + red2[row * 4 + 3]);
#pragma unroll
        for (int ki = 0; ki < 4; ++ki)
#pragma unroll
            for (int r = 0; r < 4; ++r) acc[ki][qi][r] *= rs;
    }
    bar_lgkm();   // red/red2 (Pc region) about to be overwritten

    // ---- PV: out[q=128][NV] = probs @ V, k loop in 4 chunks of 64 --------
    f32x4 opv[4][NVT] = {};
    for (int c = 0; c < 4; ++c) {
        // pack + write V chunk c from prefetched regs
        {
            union { uint2 q2[8]; u16 s[32]; } uq;
#pragma unroll
            for (int i = 0; i < 8; ++i) uq.q2[i] = vreg[i];
#pragma unroll
            for (int j = 0; j < 4; ++j) {
                const int row = n4 + j;
                const u32 v0 = (u32)uq.s[j]      | ((u32)uq.s[4 + j]  << 16);
                const u32 v1 = (u32)uq.s[8 + j]  | ((u32)uq.s[12 + j] << 16);
                const u32 v2 = (u32)uq.s[16 + j] | ((u32)uq.s[20 + j] << 16);
                const u32 v3 = (u32)uq.s[24 + j] | ((u32)uq.s[28 + j] << 16);
                const int slot = (t >> 6) ^ (row & 7);
                *reinterpret_cast<uint4*>(&Vc[row * 64 + (slot << 3)]) =
                    make_uint4(v0, v1, v2, v3);
            }
            if (NVT == 5 && t < 128) {
                union { uint2 q2[8]; u16 s[32]; } ub;
#pragma unroll
                for (int i = 0; i < 8; ++i) ub.q2[i] = vtail[i];
#pragma unroll
                for (int j = 0; j < 4; ++j) {
                    const int row = n4b + j;
                    const u32 v0 = (u32)ub.s[j]      | ((u32)ub.s[4 + j]  << 16);
                    const u32 v1 = (u32)ub.s[8 + j]  | ((u32)ub.s[12 + j] << 16);
                    const u32 v2 = (u32)ub.s[16 + j] | ((u32)ub.s[20 + j] << 16);
                    const u32 v3 = (u32)ub.s[24 + j] | ((u32)ub.s[28 + j] << 16);
                    const int slot = (t >> 4) ^ (row & 7);
                    *reinterpret_cast<uint4*>(&Vc[row * 64 + (slot << 3)]) =
                        make_uint4(v0, v1, v2, v3);
                }
            }
        }
        // owning waves write this chunk's probs (cvt_pk packed b64 writes)
        if (wk == c) {
#pragma unroll
            for (int qi = 0; qi < 4; ++qi) {
                const int qrow = wr * 64 + qi * 16 + lr;
#pragma unroll
                for (int ki = 0; ki < 4; ++ki) {
                    const u32 lo = cvt_pk(acc[ki][qi][0], acc[ki][qi][1]);
                    const u32 hi = cvt_pk(acc[ki][qi][2], acc[ki][qi][3]);
                    const int slot = ((ki << 1) + (lg >> 1)) ^ (qrow & 7);
                    *reinterpret_cast<uint2*>(
                        (char*)Pc + qrow * 128 + (slot << 4) + ((lg & 1) << 3)) =
                        make_uint2(lo, hi);
                }
            }
        }
        // T14: issue next chunk's V loads before this chunk's MFMA — these
        // survive the lgkm-only barriers below and land during the MFMAs.
        if (c < 3) {
#pragma unroll
            for (int i = 0; i < 8; ++i)
                vreg[i] = *reinterpret_cast<const uint2*>(
                    Vp + (long long)((c + 1) * 64 + k8v + i) * ldv + n4);
            if (NVT == 5 && t < 128) {
#pragma unroll
                for (int i = 0; i < 8; ++i)
                    vtail[i] = *reinterpret_cast<const uint2*>(
                        Vp + (long long)((c + 1) * 64 + k8b + i) * ldv + n4b);
            }
        }
        bar_lgkm();   // ds_writes visible; vreg prefetch stays in flight
#pragma unroll
        for (int kk = 0; kk < 2; ++kk) {
            bf16x8 pa[4], vb[NVT];
#pragma unroll
            for (int qi = 0; qi < 4; ++qi) {
                const int row = wr2 * 64 + qi * 16 + lr;
                const int slot = ((kk << 2) + lg) ^ (row & 7);
                pa[qi] = *reinterpret_cast<const bf16x8*>(&Pc[row * 64 + (slot << 3)]);
            }
#pragma unroll
            for (int vi = 0; vi < NVT; ++vi) {
                const int row = wc * (NVT * 16) + vi * 16 + lr;
                const int slot = ((kk << 2) + lg) ^ (row & 7);
                vb[vi] = *reinterpret_cast<const bf16x8*>(&Vc[row * 64 + (slot << 3)]);
            }
            __builtin_amdgcn_s_setprio(1);
#pragma unroll
            for (int qi = 0; qi < 4; ++qi)
#pragma unroll
                for (int vi = 0; vi < NVT; ++vi)
                    opv[qi][vi] = __builtin_amdgcn_mfma_f32_16x16x32_bf16(
                        pa[qi], vb[vi], opv[qi][vi], 0, 0, 0);
            __builtin_amdgcn_s_setprio(0);
        }
        bar_lgkm();   // all reads done before next chunk's ds_writes
    }

    // ---- write out --------------------------------------------------------
#pragma unroll
    for (int qi = 0; qi < 4; ++qi)
#pragma unroll
        for (int vi = 0; vi < NVT; ++vi) {
            const int gc = wc * (NVT * 16) + vi * 16 + lr;
            if (gc >= Nwrite) continue;
#pragma unroll
            for (int r = 0; r < 4; ++r) {
                const int qrow = wr2 * 64 + qi * 16 + (lg << 2) + r;
                Cp[(long long)qrow * ldc + gc] = f2bf_fast(opv[qi][vi][r]);
            }
        }
}

// ---------------------------------------------------------------------------
// Merged prep: blocks 0..16383 gather+L2norm (both sides) -> H;
// blocks 16384..18495 weight transpose+pad -> WiT/WaT/WpT/WcT;
// blocks 18496..18751 masks + POOL zero.
// ---------------------------------------------------------------------------
__global__ __launch_bounds__(256)
void prep_all(const int* __restrict__ x1, const int* __restrict__ x2,
              const float* __restrict__ emb,
              const float* __restrict__ Wi, const float* __restrict__ Wa,
              const float* __restrict__ Wp, const float* __restrict__ Wc,
              u16* __restrict__ h,
              u16* __restrict__ WiT, u16* __restrict__ WaT,
              u16* __restrict__ WpT, u16* __restrict__ WcT,
              float* __restrict__ M1f, float* __restrict__ POOL)
{
    const int blk = blockIdx.x;
    const int t = threadIdx.x;
    if (blk < 16384) {
        const int lane = t & 63;
        const long long row = (long long)blk * 4 + (t >> 6);
        const int tok = (row < 32768) ? x1[row] : x2[row - 32768];
        const float* er = emb + (long long)tok * 300;
        float vals[5];
        float ss = 0.f;
#pragma unroll
        for (int i = 0; i < 5; ++i) {
            const int c = lane + i * 64;
            const float v = (c < 300) ? er[c] : 0.f;
            vals[i] = v;
            ss = fmaf(v, v, ss);
        }
#pragma unroll
        for (int o = 32; o; o >>= 1) ss += __shfl_xor(ss, o, 64);
        const float inv = 1.0f / sqrtf(ss);
        u16* outp = h + row * 640;
#pragma unroll
        for (int i = 0; i < 5; ++i) {
            const int c = lane + i * 64;
            outp[c] = f2bf(vals[i] * inv);
        }
    } else if (blk < 18496) {
        int idx = (blk - 16384) * 256 + t;
        const float* src; u16* dst; int srcRows, srcCols, dstCols, seg1, seg2;
        if (idx < 81920)       { src = Wi; dst = WiT; srcRows = 300; srcCols = 200; dstCols = 320; seg1 = 300; seg2 = 320; }
        else if (idx < 147456) { idx -= 81920;  src = Wa; dst = WaT; srcRows = 200; srcCols = 200; dstCols = 256; seg1 = 200; seg2 = 256; }
        else if (idx < 311296) { idx -= 147456; src = Wp; dst = WpT; srcRows = 600; srcCols = 200; dstCols = 640; seg1 = 300; seg2 = 320; }
        else                   { idx -= 311296; src = Wc; dst = WcT; srcRows = 400; srcCols = 400; dstCols = 448; seg1 = 400; seg2 = 448; }
        const int n = idx / dstCols, k = idx - n * dstCols;
        int sr = -1;
        if (k < seg1) sr = k;
        else if (k >= seg2 && (k - seg2) < (srcRows - seg1)) sr = seg1 + (k - seg2);
        u16 v = 0;
        if (n < srcCols && sr >= 0) v = f2bf(src[(long long)sr * srcCols + n]);
        dst[idx] = v;
    } else {
        const int b2 = blk - 18496;         // 0..255
        const int b = b2 & 127;
        const int* x = (b2 < 128) ? x1 : x2;
        float* mask = M1f + (b2 < 128 ? 0 : 32768);
        int nz = (x[b * LSEQ + t] != 0) ? 1 : 0;
#pragma unroll
        for (int o = 32; o; o >>= 1) nz += __shfl_xor(nz, o, 64);
        __shared__ int red[4];
        if ((t & 63) == 0) red[t >> 6] = nz;
        __syncthreads();
        const int size = red[0] + red[1] + red[2] + red[3];
        mask[b * LSEQ + t] = (t < size) ? 1.0f : 0.0f;
        if (b2 < 128) {
            for (int i = t; i < 800; i += 256) POOL[b * 800 + i] = 0.f;
        }
    }
}

__global__ __launch_bounds__(256)
void final_fc(const float* __restrict__ pooled, const float* __restrict__ Wg,
              const float* __restrict__ bg, float* __restrict__ out)
{
    const int b = blockIdx.x;
    const int t = threadIdx.x;
    float a0 = 0.f, a1 = 0.f, a2 = 0.f;
    for (int k = t; k < 800; k += 256) {
        const float p = pooled[(long long)b * 800 + k];
        a0 = fmaf(p, Wg[k * 3 + 0], a0);
        a1 = fmaf(p, Wg[k * 3 + 1], a1);
        a2 = fmaf(p, Wg[k * 3 + 2], a2);
    }
#pragma unroll
    for (int o = 32; o; o >>= 1) {
        a0 += __shfl_xor(a0, o, 64);
        a1 += __shfl_xor(a1, o, 64);
        a2 += __shfl_xor(a2, o, 64);
    }
    __shared__ float r0[4], r1[4], r2[4];
    if ((t & 63) == 0) { r0[t >> 6] = a0; r1[t >> 6] = a1; r2[t >> 6] = a2; }
    __syncthreads();
    if (t == 0) {
        out[b * 3 + 0] = r0[0] + r0[1] + r0[2] + r0[3] + bg[0];
        out[b * 3 + 1] = r1[0] + r1[1] + r1[2] + r1[3] + bg[1];
        out[b * 3 + 2] = r2[0] + r2[1] + r2[2] + r2[3] + bg[2];
    }
}

// ---------------------------------------------------------------------------
extern "C" void kernel_launch(void* const* d_in, const int* in_sizes, int n_in,
                              void* d_out, int out_size, void* d_ws, size_t ws_size,
                              hipStream_t stream)
{
    (void)in_sizes; (void)n_in; (void)out_size; (void)ws_size;

    const int*   x1     = (const int*)  d_in[0];
    const int*   x2     = (const int*)  d_in[1];
    const float* emb    = (const float*)d_in[2];
    const float* Wi     = (const float*)d_in[3];
    const float* bi     = (const float*)d_in[4];
    const float* b_dist = (const float*)d_in[5];
    const float* Wp     = (const float*)d_in[6];
    const float* bp     = (const float*)d_in[7];
    const float* Wa     = (const float*)d_in[8];
    const float* ba     = (const float*)d_in[9];
    const float* Wc     = (const float*)d_in[10];
    const float* bc     = (const float*)d_in[11];
    const float* Wg     = (const float*)d_in[12];
    const float* bg     = (const float*)d_in[13];
    float* out = (float*)d_out;

    // ---- workspace (bf16 u16 unless noted) -------------------------------
    u16* wsu  = (u16*)d_ws;
    u16* H    = wsu;                       // [65536][640] e|0|xp|0
    u16* CMP  = wsu + 41943040;            // [65536][448] P|beta/alpha|0
    u16* FA   = wsu + 71303168;            // [65536][256] f / a
    u16* WiT  = wsu + 88080384;            // [256][320]
    u16* WaT  = wsu + 88162304;            // [256][256]
    u16* WpT  = wsu + 88227840;            // [256][640]
    u16* WcT  = wsu + 88391680;            // [512][448]
    float* fb = (float*)(wsu + 88621056);
    float* POOL = fb;                      // [128][800]
    float* M1f  = fb + 102400;             // [128][256]; M2f = M1f + 32768
    float* M2f  = fb + 135168;

    u16* CMP2 = CMP + (long long)32768 * 448;

    // merged prep: gather (16384) + weights (2112) + masks/pool (256)
    prep_all<<<18752, 256, 0, stream>>>(x1, x2, emb, Wi, Wa, Wp, Wc,
                                        H, WiT, WaT, WpT, WcT, M1f, POOL);

    // f = relu(e @ Wi + bi), both sides -> FA
    gemm<0, true, true><<<dim3(1, 512, 1), 512, 0, stream>>>(
        H, 640, WiT, 320, FA, 256, bi, 200, nullptr, nullptr, 320, 256);
    // fused intra attention: xp = softmax(f@f^T + dbias) @ e -> H cols 320:640
    fattn<0><<<512, 512, 0, stream>>>(FA, H, nullptr, nullptr, nullptr, nullptr, b_dist);
    // P = h @ Wp + bp -> CMP cols 0:256
    gemm<0, true, false><<<dim3(1, 512, 1), 512, 0, stream>>>(
        H, 640, WpT, 640, CMP, 448, bp, 200, nullptr, nullptr, 640, 256);
    // a = relu(P @ Wa + ba) -> FA
    gemm<0, true, true><<<dim3(1, 512, 1), 512, 0, stream>>>(
        CMP, 448, WaT, 256, FA, 256, ba, 200, nullptr, nullptr, 256, 256);
    // fused cross attention: beta/alpha -> CMP/CMP2 cols 200:448
    fattn<1><<<512, 512, 0, stream>>>(FA, nullptr, CMP, CMP2, M1f, M2f, nullptr);
    // compare + masked pool, both sides
    gemm<2, true, true><<<dim3(2, 512, 1), 512, 0, stream>>>(
        CMP, 448, WcT, 448, nullptr, 0, bc, 400, POOL, M1f, 448, 400);

    final_fc<<<NB, 256, 0, stream>>>(POOL, Wg, bg, out);
}